// Round 7
// baseline (130.387 us; speedup 1.0000x reference)
//
#include <hip/hip_runtime.h>
#include <hip/hip_bf16.h>
#include <math.h>

#define N_ 4096
#define B_ 4
#define C_ 64
#define WN 8                  // waves per attn block (each: 32 m-cols x 512 n)
#define NSEG (N_ / WN)        // 512 n per wave
#define ST2 (NSEG / 32)       // 16 steps of 32 n
#define QSCALE 0.1803368801111137f   // 0.125 * log2(e), folded into Wq

typedef __attribute__((ext_vector_type(8)))  short bf16x8;
typedef __attribute__((ext_vector_type(4)))  float f32x4;
typedef __attribute__((ext_vector_type(16))) float f32x16;
typedef __attribute__((ext_vector_type(4)))  uint  u32x4;

#define MFMA(a, b, c)   __builtin_amdgcn_mfma_f32_16x16x32_bf16(a, b, c, 0, 0, 0)
#define MFMA32(a, b, c) __builtin_amdgcn_mfma_f32_32x32x16_bf16(a, b, c, 0, 0, 0)

#if __has_builtin(__builtin_amdgcn_exp2f)
#define EXP2(x) __builtin_amdgcn_exp2f(x)
#else
#define EXP2(x) __expf((x) * 0.6931471805599453f)
#endif

static __device__ __forceinline__ uint hi_bits(float f) {
    return (__float_as_uint(f) + 0x8000u) >> 16;
}
static __device__ __forceinline__ float hi_val(float f) {
    return __uint_as_float((__float_as_uint(f) + 0x8000u) & 0xFFFF0000u);
}
// pack two f32 -> u32 of 2 bf16 (lo=a, hi=b), round-half-up
static __device__ __forceinline__ uint pk2(float a, float b) {
    return ((__float_as_uint(b) + 0x8000u) & 0xFFFF0000u) |
           ((__float_as_uint(a) + 0x8000u) >> 16);
}

// ---------------------------------------------------------------------------
// MFMA QKV projection (unchanged). Qh/Kh: [B][N][64]; Vh: [B][64][N].
// ---------------------------------------------------------------------------
__global__ __launch_bounds__(256) void qkv_mfma(
    const float* __restrict__ x,  const float* __restrict__ Wq,
    const float* __restrict__ Wk, const float* __restrict__ Wv,
    ushort* __restrict__ Qh, ushort* __restrict__ Kh, ushort* __restrict__ Vh)
{
    __shared__ float xs[C_][33];

    const int b   = blockIdx.x / (N_ / 32);
    const int n0  = (blockIdx.x % (N_ / 32)) * 32;
    const int tid = threadIdx.x;
    const int w   = tid >> 6;
    const int l   = tid & 63;
    const int lr  = l & 15;
    const int lg  = l >> 4;

    #pragma unroll
    for (int it = 0; it < 2; ++it) {
        const int i = tid + it * 256;
        const int row = i >> 3, q = i & 7;
        const float4 a = *(const float4*)(x + ((size_t)b * C_ + row) * N_ + n0 + q * 4);
        xs[row][q * 4 + 0] = a.x; xs[row][q * 4 + 1] = a.y;
        xs[row][q * 4 + 2] = a.z; xs[row][q * 4 + 3] = a.w;
    }

    bf16x8 wh[3][2], wl[3][2];
    #pragma unroll
    for (int i = 0; i < 3; ++i) {
        const int rt  = w * 3 + i;
        const int mat = rt >> 2;          // 0=q 1=k 2=v
        const int dt  = rt & 3;
        const float* __restrict__ W = (mat == 0) ? Wq : ((mat == 1) ? Wk : Wv);
        const float scale = (mat == 0) ? QSCALE : 1.0f;
        #pragma unroll
        for (int ks = 0; ks < 2; ++ks) {
            const float4* p = (const float4*)(W + (dt * 16 + lr) * C_ + ks * 32 + lg * 8);
            float4 f0 = p[0], f1 = p[1];
            float v[8] = {f0.x, f0.y, f0.z, f0.w, f1.x, f1.y, f1.z, f1.w};
            bf16x8 ht, lt;
            #pragma unroll
            for (int j = 0; j < 8; ++j) {
                const float f = v[j] * scale;
                const float h = hi_val(f);
                ht[j] = (short)(__float_as_uint(h) >> 16);
                lt[j] = (short)hi_bits(f - h);
            }
            wh[i][ks] = ht; wl[i][ks] = lt;
        }
    }
    __syncthreads();

    #pragma unroll
    for (int nt = 0; nt < 2; ++nt) {
        bf16x8 xh[2], xl[2];
        #pragma unroll
        for (int ks = 0; ks < 2; ++ks) {
            bf16x8 ht, lt;
            #pragma unroll
            for (int j = 0; j < 8; ++j) {
                const float f = xs[ks * 32 + lg * 8 + j][nt * 16 + lr];
                const float h = hi_val(f);
                ht[j] = (short)(__float_as_uint(h) >> 16);
                lt[j] = (short)hi_bits(f - h);
            }
            xh[ks] = ht; xl[ks] = lt;
        }

        #pragma unroll
        for (int i = 0; i < 3; ++i) {
            const int rt  = w * 3 + i;
            const int mat = rt >> 2;
            const int dt  = rt & 3;
            f32x4 acc = (f32x4){0.f, 0.f, 0.f, 0.f};
            if (mat < 2) {
                #pragma unroll
                for (int ks = 0; ks < 2; ++ks) {
                    acc = MFMA(wh[i][ks], xh[ks], acc);
                    acc = MFMA(wh[i][ks], xl[ks], acc);
                    acc = MFMA(wl[i][ks], xh[ks], acc);
                }
                ushort* __restrict__ H = mat ? Kh : Qh;
                const size_t base = ((size_t)b * N_ + n0 + nt * 16 + lr) * C_ + dt * 16 + lg * 4;
                *(uint2*)(H + base) = make_uint2((hi_bits(acc[1]) << 16) | hi_bits(acc[0]),
                                                 (hi_bits(acc[3]) << 16) | hi_bits(acc[2]));
            } else {
                #pragma unroll
                for (int ks = 0; ks < 2; ++ks) {
                    acc = MFMA(xh[ks], wh[i][ks], acc);
                    acc = MFMA(xl[ks], wh[i][ks], acc);
                    acc = MFMA(xh[ks], wl[i][ks], acc);
                }
                const size_t base = ((size_t)b * C_ + dt * 16 + lr) * N_ + n0 + nt * 16 + lg * 4;
                *(uint2*)(Vh + base) = make_uint2((hi_bits(acc[1]) << 16) | hi_bits(acc[0]),
                                                  (hi_bits(acc[3]) << 16) | hi_bits(acc[2]));
            }
        }
    }
}

// ---------------------------------------------------------------------------
// Barrier-free attention. Block = 32 m-cols, 8 independent waves (n-split 8).
// 32x32x16 MFMA, swapped-operand S (A=Q, B=K) puts m in lanes / n in regs:
// E is packed in-register (pk2) and exchanged across lane-halves via
// __shfl_xor(32) to form the PV B-frag. No LDS, no barriers in the loop.
// Epilogue: 3-round LDS tree reduction of the 8 waves' partials.
// ---------------------------------------------------------------------------
__global__ __launch_bounds__(512, 4) void attn_mfma(
    const ushort* __restrict__ Qh, const ushort* __restrict__ Kh,
    const ushort* __restrict__ Vh, float* __restrict__ out)
{
    __shared__ float obuf[4][2048];   // 32 KB reduction scratch
    __shared__ float lred[WN][32];

    // XCD swizzle: batch b pinned to XCD pair {2b, 2b+1}
    const int bid = blockIdx.x;
    const int b   = (bid & 7) >> 1;
    const int mt  = (bid & 1) + ((bid >> 3) << 1);   // 0..127
    const int tid = threadIdx.x;
    const int w   = tid >> 6;
    const int l   = tid & 63;
    const int lm  = l & 31;
    const int hi  = l >> 5;
    const int m0  = mt * 32;

    // resident K B-frags: B[k=d][col=m], d-tile dt -> k = dt*16 + hi*8 + j
    bf16x8 kb[4];
    #pragma unroll
    for (int dt = 0; dt < 4; ++dt)
        kb[dt] = *(const bf16x8*)(Kh + ((size_t)b * N_ + m0 + lm) * C_ + dt * 16 + hi * 8);

    f32x16 occ0, occ1;
    #pragma unroll
    for (int r = 0; r < 16; ++r) { occ0[r] = 0.f; occ1[r] = 0.f; }
    float den = 0.f;

    const int n0 = w * NSEG;
    const ushort* __restrict__ Qb = Qh + (size_t)b * N_ * C_;
    const ushort* __restrict__ Vb = Vh + (size_t)b * C_ * N_;

    for (int t = 0; t < ST2; ++t) {
        const int nb = n0 + t * 32;

        // V A-frags (V[row=o][k=n]) — issue early, consumed at PV
        bf16x8 va[4];   // [ot*2 + ks]
        #pragma unroll
        for (int ot = 0; ot < 2; ++ot)
            #pragma unroll
            for (int ks = 0; ks < 2; ++ks)
                va[ot * 2 + ks] = *(const bf16x8*)(Vb + ((size_t)(ot * 32 + lm)) * N_ + nb + ks * 16 + hi * 8);

        // Q A-frags (Q[row=n][k=d])
        bf16x8 qa[4];
        #pragma unroll
        for (int dt = 0; dt < 4; ++dt)
            qa[dt] = *(const bf16x8*)(Qb + ((size_t)(nb + lm)) * C_ + dt * 16 + hi * 8);

        // S[n][m]: C col = m (lanes), row = n (regs)
        f32x16 s;
        #pragma unroll
        for (int r = 0; r < 16; ++r) s[r] = 0.f;
        #pragma unroll
        for (int dt = 0; dt < 4; ++dt)
            s = MFMA32(qa[dt], kb[dt], s);

        // E = exp2(s); den; pack pairs (n rows 2g,2g+1 within this lane's half)
        float e[16];
        #pragma unroll
        for (int r = 0; r < 16; ++r) e[r] = EXP2(s[r]);
        #pragma unroll
        for (int r = 0; r < 16; r += 4)
            den += ((e[r] + e[r + 1]) + (e[r + 2] + e[r + 3]));
        uint P[8];
        #pragma unroll
        for (int g = 0; g < 8; ++g) P[g] = pk2(e[2 * g], e[2 * g + 1]);

        // exchange halves: partner's packed words
        uint sw[8];
        #pragma unroll
        for (int g = 0; g < 8; ++g) sw[g] = __shfl_xor(P[g], 32);

        // PV B-frags: B[k=n-local][col=m]; k = ks*16 + hi*8 + j
        u32x4 t0, t1;
        t0.x = hi ? sw[2] : P[0];  t0.y = hi ? sw[3] : P[1];
        t0.z = hi ? P[2]  : sw[0]; t0.w = hi ? P[3]  : sw[1];
        t1.x = hi ? sw[6] : P[4];  t1.y = hi ? sw[7] : P[5];
        t1.z = hi ? P[6]  : sw[4]; t1.w = hi ? P[7]  : sw[5];
        const bf16x8 eb0 = __builtin_bit_cast(bf16x8, t0);
        const bf16x8 eb1 = __builtin_bit_cast(bf16x8, t1);

        occ0 = MFMA32(va[0], eb0, occ0);
        occ0 = MFMA32(va[1], eb1, occ0);
        occ1 = MFMA32(va[2], eb0, occ1);
        occ1 = MFMA32(va[3], eb1, occ1);
    }

    // ---- epilogue: reduce 8 waves' partials ----
    den += __shfl_xor(den, 32);
    if (l < 32) lred[w][lm] = den;

    // round 1: waves 4-7 stage; 0-3 accumulate
    if (w >= 4) {
        float* dst = obuf[w - 4];
        #pragma unroll
        for (int r = 0; r < 16; ++r) {
            const int o = (r & 3) + 8 * (r >> 2) + 4 * hi;
            dst[o * 32 + lm]        = occ0[r];
            dst[(o + 32) * 32 + lm] = occ1[r];
        }
    }
    __syncthreads();
    if (w < 4) {
        const float* src = obuf[w];
        #pragma unroll
        for (int r = 0; r < 16; ++r) {
            const int o = (r & 3) + 8 * (r >> 2) + 4 * hi;
            occ0[r] += src[o * 32 + lm];
            occ1[r] += src[(o + 32) * 32 + lm];
        }
    }
    __syncthreads();
    // round 2: waves 2-3 stage; 0-1 accumulate
    if (w == 2 || w == 3) {
        float* dst = obuf[w - 2];
        #pragma unroll
        for (int r = 0; r < 16; ++r) {
            const int o = (r & 3) + 8 * (r >> 2) + 4 * hi;
            dst[o * 32 + lm]        = occ0[r];
            dst[(o + 32) * 32 + lm] = occ1[r];
        }
    }
    __syncthreads();
    if (w < 2) {
        const float* src = obuf[w];
        #pragma unroll
        for (int r = 0; r < 16; ++r) {
            const int o = (r & 3) + 8 * (r >> 2) + 4 * hi;
            occ0[r] += src[o * 32 + lm];
            occ1[r] += src[(o + 32) * 32 + lm];
        }
    }
    __syncthreads();
    // round 3: wave 1 stages; wave 0 finishes + writes
    if (w == 1) {
        float* dst = obuf[0];
        #pragma unroll
        for (int r = 0; r < 16; ++r) {
            const int o = (r & 3) + 8 * (r >> 2) + 4 * hi;
            dst[o * 32 + lm]        = occ0[r];
            dst[(o + 32) * 32 + lm] = occ1[r];
        }
    }
    __syncthreads();
    if (w == 0) {
        float dtot = 0.f;
        #pragma unroll
        for (int i = 0; i < WN; ++i) dtot += lred[i][lm];
        const float inv = __builtin_amdgcn_rcpf(dtot);
        const float* src = obuf[0];
        #pragma unroll
        for (int r = 0; r < 16; ++r) {
            const int o = (r & 3) + 8 * (r >> 2) + 4 * hi;
            out[((size_t)b * C_ + o) * N_ + m0 + lm] =
                (occ0[r] + src[o * 32 + lm]) * inv;
            out[((size_t)b * C_ + o + 32) * N_ + m0 + lm] =
                (occ1[r] + src[(o + 32) * 32 + lm]) * inv;
        }
    }
}

// ---------------------------------------------------------------------------
extern "C" void kernel_launch(void* const* d_in, const int* in_sizes, int n_in,
                              void* d_out, int out_size, void* d_ws, size_t ws_size,
                              hipStream_t stream)
{
    const float* x  = (const float*)d_in[0];
    const float* Wq = (const float*)d_in[1];
    const float* Wk = (const float*)d_in[2];
    const float* Wv = (const float*)d_in[3];
    float* out = (float*)d_out;

    const size_t NE = (size_t)B_ * N_ * C_;
    ushort* Qh = (ushort*)d_ws;
    ushort* Kh = Qh + NE;
    ushort* Vh = Kh + NE;

    qkv_mfma<<<B_ * (N_ / 32), 256, 0, stream>>>(x, Wq, Wk, Wv, Qh, Kh, Vh);
    attn_mfma<<<B_ * (N_ / 32), 512, 0, stream>>>(Qh, Kh, Vh, out);
}

// Round 10
// 127.191 us; speedup vs baseline: 1.0251x; 1.0251x over previous
//
#include <hip/hip_runtime.h>
#include <hip/hip_bf16.h>
#include <math.h>

#define N_ 4096
#define B_ 4
#define C_ 64
#define MT 32                 // m-columns per attn block
#define NT 128                // n per step
#define HSEG 2048             // n per 4-wave group (2 groups per block)
#define STEPS (HSEG / NT)     // 16
#define QSCALE 0.1803368801111137f   // 0.125 * log2(e), folded into Wq

typedef __attribute__((ext_vector_type(8))) short bf16x8;
typedef __attribute__((ext_vector_type(4))) float f32x4;
#define MFMA(a, b, c) __builtin_amdgcn_mfma_f32_16x16x32_bf16(a, b, c, 0, 0, 0)

#if __has_builtin(__builtin_amdgcn_exp2f)
#define EXP2(x) __builtin_amdgcn_exp2f(x)
#else
#define EXP2(x) __expf((x) * 0.6931471805599453f)
#endif

static __device__ __forceinline__ uint hi_bits(float f) {
    return (__float_as_uint(f) + 0x8000u) >> 16;
}
static __device__ __forceinline__ float hi_val(float f) {
    return __uint_as_float((__float_as_uint(f) + 0x8000u) & 0xFFFF0000u);
}

// ---------------------------------------------------------------------------
// MFMA QKV projection (unchanged, known-good). Qh/Kh: [B][N][64]; Vh: [B][64][N].
// ---------------------------------------------------------------------------
__global__ __launch_bounds__(256) void qkv_mfma(
    const float* __restrict__ x,  const float* __restrict__ Wq,
    const float* __restrict__ Wk, const float* __restrict__ Wv,
    ushort* __restrict__ Qh, ushort* __restrict__ Kh, ushort* __restrict__ Vh)
{
    __shared__ float xs[C_][33];

    const int b   = blockIdx.x / (N_ / 32);
    const int n0  = (blockIdx.x % (N_ / 32)) * 32;
    const int tid = threadIdx.x;
    const int w   = tid >> 6;
    const int l   = tid & 63;
    const int lr  = l & 15;
    const int lg  = l >> 4;

    #pragma unroll
    for (int it = 0; it < 2; ++it) {
        const int i = tid + it * 256;
        const int row = i >> 3, q = i & 7;
        const float4 a = *(const float4*)(x + ((size_t)b * C_ + row) * N_ + n0 + q * 4);
        xs[row][q * 4 + 0] = a.x; xs[row][q * 4 + 1] = a.y;
        xs[row][q * 4 + 2] = a.z; xs[row][q * 4 + 3] = a.w;
    }

    bf16x8 wh[3][2], wl[3][2];
    #pragma unroll
    for (int i = 0; i < 3; ++i) {
        const int rt  = w * 3 + i;
        const int mat = rt >> 2;          // 0=q 1=k 2=v
        const int dt  = rt & 3;
        const float* __restrict__ W = (mat == 0) ? Wq : ((mat == 1) ? Wk : Wv);
        const float scale = (mat == 0) ? QSCALE : 1.0f;
        #pragma unroll
        for (int ks = 0; ks < 2; ++ks) {
            const float4* p = (const float4*)(W + (dt * 16 + lr) * C_ + ks * 32 + lg * 8);
            float4 f0 = p[0], f1 = p[1];
            float v[8] = {f0.x, f0.y, f0.z, f0.w, f1.x, f1.y, f1.z, f1.w};
            bf16x8 ht, lt;
            #pragma unroll
            for (int j = 0; j < 8; ++j) {
                const float f = v[j] * scale;
                const float h = hi_val(f);
                ht[j] = (short)(__float_as_uint(h) >> 16);
                lt[j] = (short)hi_bits(f - h);
            }
            wh[i][ks] = ht; wl[i][ks] = lt;
        }
    }
    __syncthreads();

    #pragma unroll
    for (int nt = 0; nt < 2; ++nt) {
        bf16x8 xh[2], xl[2];
        #pragma unroll
        for (int ks = 0; ks < 2; ++ks) {
            bf16x8 ht, lt;
            #pragma unroll
            for (int j = 0; j < 8; ++j) {
                const float f = xs[ks * 32 + lg * 8 + j][nt * 16 + lr];
                const float h = hi_val(f);
                ht[j] = (short)(__float_as_uint(h) >> 16);
                lt[j] = (short)hi_bits(f - h);
            }
            xh[ks] = ht; xl[ks] = lt;
        }

        #pragma unroll
        for (int i = 0; i < 3; ++i) {
            const int rt  = w * 3 + i;
            const int mat = rt >> 2;
            const int dt  = rt & 3;
            f32x4 acc = (f32x4){0.f, 0.f, 0.f, 0.f};
            if (mat < 2) {
                #pragma unroll
                for (int ks = 0; ks < 2; ++ks) {
                    acc = MFMA(wh[i][ks], xh[ks], acc);
                    acc = MFMA(wh[i][ks], xl[ks], acc);
                    acc = MFMA(wl[i][ks], xh[ks], acc);
                }
                ushort* __restrict__ H = mat ? Kh : Qh;
                const size_t base = ((size_t)b * N_ + n0 + nt * 16 + lr) * C_ + dt * 16 + lg * 4;
                *(uint2*)(H + base) = make_uint2((hi_bits(acc[1]) << 16) | hi_bits(acc[0]),
                                                 (hi_bits(acc[3]) << 16) | hi_bits(acc[2]));
            } else {
                #pragma unroll
                for (int ks = 0; ks < 2; ++ks) {
                    acc = MFMA(xh[ks], wh[i][ks], acc);
                    acc = MFMA(xl[ks], wh[i][ks], acc);
                    acc = MFMA(xh[ks], wl[i][ks], acc);
                }
                const size_t base = ((size_t)b * C_ + dt * 16 + lr) * N_ + n0 + nt * 16 + lg * 4;
                *(uint2*)(Vh + base) = make_uint2((hi_bits(acc[1]) << 16) | hi_bits(acc[0]),
                                                  (hi_bits(acc[3]) << 16) | hi_bits(acc[2]));
            }
        }
    }
}

// ---------------------------------------------------------------------------
// Attention: block = 32 m-cols, 8 waves = two INDEPENDENT 4-wave groups,
// group g2 owns n in [g2*2048, g2*2048+2048). Per 128-n step each wave
// computes 32 S-rows, exp2 -> bf16 E into rotation-swizzled double-buffered
// LDS (per-group), one barrier, PV over its 16 o-rows. Epilogue (R8 fix:
// DRAIN BARRIER before reusing Em as scratch) merges groups and writes out.
// ---------------------------------------------------------------------------
__global__ __launch_bounds__(512, 4) void attn_mfma(
    const ushort* __restrict__ Qh, const ushort* __restrict__ Kh,
    const ushort* __restrict__ Vh, float* __restrict__ out)
{
    __shared__ ushort Em[2][2][MT * NT];   // [group][buf][m*n] = 32 KB
    __shared__ float red[8][MT];

    // XCD swizzle: batch b pinned to XCD pair {2b, 2b+1}; grid 512 bijective
    const int bid = blockIdx.x;
    const int b   = (bid & 7) >> 1;
    const int mt  = (bid & 1) + ((bid >> 3) << 1);   // 0..127
    const int tid = threadIdx.x;
    const int w   = tid >> 6;             // 0..7
    const int g2  = w >> 2;               // n-half group
    const int w4  = w & 3;                // wave within group
    const int l   = tid & 63;
    const int lr  = l & 15;
    const int lg  = l >> 4;
    const int m0  = mt * MT;
    const int nG  = g2 * HSEG;

    // resident K B-frags (2 m-tiles)
    bf16x8 khf[2][2];
    #pragma unroll
    for (int f = 0; f < 2; ++f)
        #pragma unroll
        for (int ks = 0; ks < 2; ++ks)
            khf[f][ks] = *(const bf16x8*)(Kh + ((size_t)b * N_ + m0 + f * 16 + lr) * C_ + ks * 32 + lg * 8);

    f32x4 oacc[2];
    oacc[0] = (f32x4){0.f, 0.f, 0.f, 0.f};
    oacc[1] = (f32x4){0.f, 0.f, 0.f, 0.f};
    float den[2] = {0.f, 0.f};

    // Q A-frags for step 0 (wave's 32 n-rows)
    bf16x8 qcur[2][2];
    #pragma unroll
    for (int nt2 = 0; nt2 < 2; ++nt2)
        #pragma unroll
        for (int ks = 0; ks < 2; ++ks)
            qcur[nt2][ks] = *(const bf16x8*)(Qh + ((size_t)b * N_ + nG + w4 * 32 + nt2 * 16 + lr) * C_ + ks * 32 + lg * 8);

    for (int t = 0; t < STEPS; ++t) {
        const int nbase = nG + t * NT;
        const int buf   = t & 1;

        // V A-frags — issued early, consumed after the barrier
        bf16x8 vh[4];
        #pragma unroll
        for (int ks = 0; ks < 4; ++ks)
            vh[ks] = *(const bf16x8*)(Vh + ((size_t)b * C_ + w4 * 16 + lr) * N_ + nbase + ks * 32 + lg * 8);

        // S = Q·K (32 n-rows x 32 m)
        f32x4 s2[2][2];
        #pragma unroll
        for (int nt2 = 0; nt2 < 2; ++nt2)
            #pragma unroll
            for (int f = 0; f < 2; ++f) s2[nt2][f] = (f32x4){0.f, 0.f, 0.f, 0.f};
        __builtin_amdgcn_s_setprio(1);
        #pragma unroll
        for (int ks = 0; ks < 2; ++ks)
            #pragma unroll
            for (int nt2 = 0; nt2 < 2; ++nt2)
                #pragma unroll
                for (int f = 0; f < 2; ++f)
                    s2[nt2][f] = MFMA(qcur[nt2][ks], khf[f][ks], s2[nt2][f]);
        __builtin_amdgcn_s_setprio(0);

        // prefetch next step's Q
        const int tn = (t + 1 < STEPS) ? (t + 1) : t;
        bf16x8 qnext[2][2];
        #pragma unroll
        for (int nt2 = 0; nt2 < 2; ++nt2)
            #pragma unroll
            for (int ks = 0; ks < 2; ++ks)
                qnext[nt2][ks] = *(const bf16x8*)(Qh + ((size_t)b * N_ + nG + tn * NT + w4 * 32 + nt2 * 16 + lr) * C_ + ks * 32 + lg * 8);

        // E = exp2(s) -> bf16, den accumulate, swizzled LDS write
        #pragma unroll
        for (int nt2 = 0; nt2 < 2; ++nt2)
            #pragma unroll
            for (int f = 0; f < 2; ++f) {
                const float e0 = EXP2(s2[nt2][f][0]);
                const float e1 = EXP2(s2[nt2][f][1]);
                const float e2 = EXP2(s2[nt2][f][2]);
                const float e3 = EXP2(s2[nt2][f][3]);
                den[f] += (e0 + e1) + (e2 + e3);
                const uint u0 = __float_as_uint(e0) + 0x8000u;
                const uint u1 = __float_as_uint(e1) + 0x8000u;
                const uint u2 = __float_as_uint(e2) + 0x8000u;
                const uint u3 = __float_as_uint(e3) + 0x8000u;
                const int row = f * 16 + lr;
                const int g   = w4 * 4 + nt2 * 2 + (lg >> 1);   // n-group of 8
                *(uint2*)&Em[g2][buf][row * NT + (((g + row) & 15) << 3) + ((lg & 1) << 2)] =
                    make_uint2((u1 & 0xFFFF0000u) | (u0 >> 16), (u3 & 0xFFFF0000u) | (u2 >> 16));
            }
        __syncthreads();

        // PV: out[o][m] += V[o][n] * E[n][m]
        __builtin_amdgcn_s_setprio(1);
        #pragma unroll
        for (int ks = 0; ks < 4; ++ks)
            #pragma unroll
            for (int f = 0; f < 2; ++f) {
                const int row = f * 16 + lr;
                const bf16x8 eb = *(const bf16x8*)&Em[g2][buf][row * NT + (((ks * 4 + lg + row) & 15) << 3)];
                oacc[f] = MFMA(vh[ks], eb, oacc[f]);
            }
        __builtin_amdgcn_s_setprio(0);

        #pragma unroll
        for (int nt2 = 0; nt2 < 2; ++nt2) {
            qcur[nt2][0] = qnext[nt2][0];
            qcur[nt2][1] = qnext[nt2][1];
        }
    }

    // ---- epilogue ----
    // R8 FIX: drain barrier — ALL waves must finish their last PV read of Em
    // before Em is reused as f32 scratch (scr spans Em[1][0] AND 256 B of
    // Em[1][1], which the old code clobbered while laggard waves still read).
    __syncthreads();

    #pragma unroll
    for (int f = 0; f < 2; ++f) {
        den[f] += __shfl_xor(den[f], 16);
        den[f] += __shfl_xor(den[f], 32);
    }
    if (lg == 0) {
        red[w][lr]      = den[0];
        red[w][16 + lr] = den[1];
    }
    float* scr = (float*)&Em[1][0][0];    // 64 o x 33 floats = 8.4 KB (Em dead now)
    if (w >= 4) {
        #pragma unroll
        for (int f = 0; f < 2; ++f)
            #pragma unroll
            for (int r = 0; r < 4; ++r)
                scr[(w4 * 16 + lg * 4 + r) * 33 + f * 16 + lr] = oacc[f][r];
    }
    __syncthreads();

    if (w < 4) {
        float inv[2];
        #pragma unroll
        for (int f = 0; f < 2; ++f) {
            const int m = f * 16 + lr;
            inv[f] = __builtin_amdgcn_rcpf(red[0][m] + red[1][m] + red[2][m] + red[3][m] +
                                           red[4][m] + red[5][m] + red[6][m] + red[7][m]);
        }
        #pragma unroll
        for (int f = 0; f < 2; ++f)
            #pragma unroll
            for (int r = 0; r < 4; ++r) {
                const int o = w4 * 16 + lg * 4 + r;
                out[((size_t)b * C_ + o) * N_ + m0 + f * 16 + lr] =
                    (oacc[f][r] + scr[o * 33 + f * 16 + lr]) * inv[f];
            }
    }
}

// ---------------------------------------------------------------------------
extern "C" void kernel_launch(void* const* d_in, const int* in_sizes, int n_in,
                              void* d_out, int out_size, void* d_ws, size_t ws_size,
                              hipStream_t stream)
{
    const float* x  = (const float*)d_in[0];
    const float* Wq = (const float*)d_in[1];
    const float* Wk = (const float*)d_in[2];
    const float* Wv = (const float*)d_in[3];
    float* out = (float*)d_out;

    const size_t NE = (size_t)B_ * N_ * C_;
    ushort* Qh = (ushort*)d_ws;
    ushort* Kh = Qh + NE;
    ushort* Vh = Kh + NE;

    qkv_mfma<<<B_ * (N_ / 32), 256, 0, stream>>>(x, Wq, Wk, Wv, Qh, Kh, Vh);
    attn_mfma<<<B_ * (N_ / MT), 512, 0, stream>>>(Qh, Kh, Vh, out);
}

// Round 11
// 95.315 us; speedup vs baseline: 1.3680x; 1.3344x over previous
//
#include <hip/hip_runtime.h>
#include <hip/hip_bf16.h>
#include <math.h>

#define N_ 4096
#define B_ 4
#define C_ 64
#define MT 64                 // m-columns per attn block
#define NT 128                // n per step
#define SPLITN 2              // n-splits (partials added; no max needed)
#define HSEG (N_ / SPLITN)    // 2048
#define STEPS (HSEG / NT)     // 16
#define QSCALE 0.1803368801111137f   // 0.125 * log2(e), folded into Wq

typedef __attribute__((ext_vector_type(8))) short bf16x8;
typedef __attribute__((ext_vector_type(4))) float f32x4;
#define MFMA(a, b, c) __builtin_amdgcn_mfma_f32_16x16x32_bf16(a, b, c, 0, 0, 0)

#if __has_builtin(__builtin_amdgcn_exp2f)
#define EXP2(x) __builtin_amdgcn_exp2f(x)
#else
#define EXP2(x) __expf((x) * 0.6931471805599453f)
#endif

static __device__ __forceinline__ uint hi_bits(float f) {
    return (__float_as_uint(f) + 0x8000u) >> 16;
}
static __device__ __forceinline__ float hi_val(float f) {
    return __uint_as_float((__float_as_uint(f) + 0x8000u) & 0xFFFF0000u);
}

// ---------------------------------------------------------------------------
// MFMA QKV projection -> FRAGMENT-MAJOR layouts (each attn fragment load
// becomes one contiguous 1-KB wave read: base + lane*16B).
//  Qf/Kf: [B][N/16][ks=2][lane=64][8]   (lane = lg_a*16+lr_a holds
//          row n=tile*16+lr_a, d=ks*32+lg_a*8+j)
//  Vf:    [B][ot=4][N/32][lane=64][8]   (lane holds o=ot*16+lr_a,
//          n=nc*32+lg_a*8+j)
// Mapping from qkv's C-layout (lane holds 4 consecutive d for one n, or
// 4 consecutive n for one o): ks=dt>>1, lg_a=(dt&1)*2+(lg>>1), j0=(lg&1)*4
// (Q/K);  lg_a=nt*2+(lg>>1), j0=(lg&1)*4 (V).
// ---------------------------------------------------------------------------
__global__ __launch_bounds__(256) void qkv_mfma(
    const float* __restrict__ x,  const float* __restrict__ Wq,
    const float* __restrict__ Wk, const float* __restrict__ Wv,
    ushort* __restrict__ Qf, ushort* __restrict__ Kf, ushort* __restrict__ Vf)
{
    __shared__ float xs[C_][33];

    const int b   = blockIdx.x / (N_ / 32);
    const int n0  = (blockIdx.x % (N_ / 32)) * 32;
    const int tid = threadIdx.x;
    const int w   = tid >> 6;
    const int l   = tid & 63;
    const int lr  = l & 15;
    const int lg  = l >> 4;

    #pragma unroll
    for (int it = 0; it < 2; ++it) {
        const int i = tid + it * 256;
        const int row = i >> 3, q = i & 7;
        const float4 a = *(const float4*)(x + ((size_t)b * C_ + row) * N_ + n0 + q * 4);
        xs[row][q * 4 + 0] = a.x; xs[row][q * 4 + 1] = a.y;
        xs[row][q * 4 + 2] = a.z; xs[row][q * 4 + 3] = a.w;
    }

    bf16x8 wh[3][2], wl[3][2];
    #pragma unroll
    for (int i = 0; i < 3; ++i) {
        const int rt  = w * 3 + i;
        const int mat = rt >> 2;          // 0=q 1=k 2=v
        const int dt  = rt & 3;
        const float* __restrict__ W = (mat == 0) ? Wq : ((mat == 1) ? Wk : Wv);
        const float scale = (mat == 0) ? QSCALE : 1.0f;
        #pragma unroll
        for (int ks = 0; ks < 2; ++ks) {
            const float4* p = (const float4*)(W + (dt * 16 + lr) * C_ + ks * 32 + lg * 8);
            float4 f0 = p[0], f1 = p[1];
            float v[8] = {f0.x, f0.y, f0.z, f0.w, f1.x, f1.y, f1.z, f1.w};
            bf16x8 ht, lt;
            #pragma unroll
            for (int j = 0; j < 8; ++j) {
                const float f = v[j] * scale;
                const float h = hi_val(f);
                ht[j] = (short)(__float_as_uint(h) >> 16);
                lt[j] = (short)hi_bits(f - h);
            }
            wh[i][ks] = ht; wl[i][ks] = lt;
        }
    }
    __syncthreads();

    #pragma unroll
    for (int nt = 0; nt < 2; ++nt) {
        bf16x8 xh[2], xl[2];
        #pragma unroll
        for (int ks = 0; ks < 2; ++ks) {
            bf16x8 ht, lt;
            #pragma unroll
            for (int j = 0; j < 8; ++j) {
                const float f = xs[ks * 32 + lg * 8 + j][nt * 16 + lr];
                const float h = hi_val(f);
                ht[j] = (short)(__float_as_uint(h) >> 16);
                lt[j] = (short)hi_bits(f - h);
            }
            xh[ks] = ht; xl[ks] = lt;
        }

        #pragma unroll
        for (int i = 0; i < 3; ++i) {
            const int rt  = w * 3 + i;
            const int mat = rt >> 2;
            const int dt  = rt & 3;
            f32x4 acc = (f32x4){0.f, 0.f, 0.f, 0.f};
            if (mat < 2) {              // C[row=d][col=n] : lane=(lr,lg) has n=nt*16+lr, d=dt*16+lg*4+r
                #pragma unroll
                for (int ks = 0; ks < 2; ++ks) {
                    acc = MFMA(wh[i][ks], xh[ks], acc);
                    acc = MFMA(wh[i][ks], xl[ks], acc);
                    acc = MFMA(wl[i][ks], xh[ks], acc);
                }
                const uint2 pk = make_uint2((hi_bits(acc[1]) << 16) | hi_bits(acc[0]),
                                            (hi_bits(acc[3]) << 16) | hi_bits(acc[2]));
                ushort* __restrict__ H = mat ? Kf : Qf;
                const int tile = (n0 >> 4) + nt;
                const int ksq  = dt >> 1;
                const int lga  = (dt & 1) * 2 + (lg >> 1);
                const int j0   = (lg & 1) * 4;
                const size_t addr = (((size_t)b * (N_ / 16) + tile) * 2 + ksq) * 512
                                  + (lga * 16 + lr) * 8 + j0;
                *(uint2*)(H + addr) = pk;
            } else {                    // C[row=n][col=o] : lane has o=dt*16+lr, n=n0+nt*16+lg*4+r
                #pragma unroll
                for (int ks = 0; ks < 2; ++ks) {
                    acc = MFMA(xh[ks], wh[i][ks], acc);
                    acc = MFMA(xl[ks], wh[i][ks], acc);
                    acc = MFMA(xh[ks], wl[i][ks], acc);
                }
                const uint2 pk = make_uint2((hi_bits(acc[1]) << 16) | hi_bits(acc[0]),
                                            (hi_bits(acc[3]) << 16) | hi_bits(acc[2]));
                const int nc  = n0 >> 5;
                const int lga = nt * 2 + (lg >> 1);
                const int j0  = (lg & 1) * 4;
                const size_t addr = (((size_t)b * 4 + dt) * (N_ / 32) + nc) * 512
                                  + (lga * 16 + lr) * 8 + j0;
                *(uint2*)(Vf + addr) = pk;
            }
        }
    }
}

// ---------------------------------------------------------------------------
// Attention partial (R5 main-loop structure, verified): block = 64 m-cols,
// 4 waves, one n-half (SPLITN=2 -> 512 blocks, 2/CU). ALL fragment loads are
// contiguous 1-KB wave reads from the fragment-major layouts. Em swizzle,
// barrier placement, epilogue identical to the verified R4/R5 code paths.
// ---------------------------------------------------------------------------
__global__ __launch_bounds__(256, 2) void attn_mfma(
    const ushort* __restrict__ Qf, const ushort* __restrict__ Kf,
    const ushort* __restrict__ Vf,
    float* __restrict__ pacc, float* __restrict__ pden)
{
    __shared__ ushort Em[2][MT * NT];     // 32 KB, rotation-swizzled
    __shared__ float red[4][MT];

    // XCD pinning: xcd = bid&7 carries (b, n-half); same-(b,p) blocks share L2
    const int bid = blockIdx.x;
    const int xcd = bid & 7;
    const int mt  = bid >> 3;             // 0..63
    const int b   = xcd >> 1;
    const int p   = xcd & 1;
    const int tid = threadIdx.x;
    const int w   = tid >> 6;
    const int l   = tid & 63;
    const int lr  = l & 15;
    const int lg  = l >> 4;
    const int m0  = mt * MT;
    const int nG  = p * HSEG;

    // resident K B-frags: 8 contiguous 1-KB reads
    bf16x8 khf[4][2];
    #pragma unroll
    for (int f = 0; f < 4; ++f)
        #pragma unroll
        for (int ks = 0; ks < 2; ++ks)
            khf[f][ks] = *(const bf16x8*)(Kf + (((size_t)b * (N_ / 16) + (m0 >> 4) + f) * 2 + ks) * 512 + l * 8);

    f32x4 oacc[4];
    #pragma unroll
    for (int f = 0; f < 4; ++f) oacc[f] = (f32x4){0.f, 0.f, 0.f, 0.f};
    float den[4] = {0.f, 0.f, 0.f, 0.f};

    // Q A-frags for step 0 (wave's 32 n-rows = 2 tiles)
    bf16x8 qcur[2][2];
    #pragma unroll
    for (int nt2 = 0; nt2 < 2; ++nt2)
        #pragma unroll
        for (int ks = 0; ks < 2; ++ks)
            qcur[nt2][ks] = *(const bf16x8*)(Qf + (((size_t)b * (N_ / 16) + (nG >> 4) + w * 2 + nt2) * 2 + ks) * 512 + l * 8);

    for (int t = 0; t < STEPS; ++t) {
        const int nbase = nG + t * NT;
        const int buf   = t & 1;

        // V A-frags — 4 contiguous 1-KB reads, issued early
        bf16x8 vh[4];
        #pragma unroll
        for (int ks = 0; ks < 4; ++ks)
            vh[ks] = *(const bf16x8*)(Vf + (((size_t)b * 4 + w) * (N_ / 32) + (nbase >> 5) + ks) * 512 + l * 8);

        // S = Q·K (32 n-rows x 64 m)
        f32x4 s2[2][4];
        #pragma unroll
        for (int nt2 = 0; nt2 < 2; ++nt2)
            #pragma unroll
            for (int f = 0; f < 4; ++f) s2[nt2][f] = (f32x4){0.f, 0.f, 0.f, 0.f};
        __builtin_amdgcn_s_setprio(1);
        #pragma unroll
        for (int ks = 0; ks < 2; ++ks)
            #pragma unroll
            for (int nt2 = 0; nt2 < 2; ++nt2)
                #pragma unroll
                for (int f = 0; f < 4; ++f)
                    s2[nt2][f] = MFMA(qcur[nt2][ks], khf[f][ks], s2[nt2][f]);
        __builtin_amdgcn_s_setprio(0);

        // prefetch next step's Q
        const int tn = (t + 1 < STEPS) ? (t + 1) : t;
        bf16x8 qnext[2][2];
        #pragma unroll
        for (int nt2 = 0; nt2 < 2; ++nt2)
            #pragma unroll
            for (int ks = 0; ks < 2; ++ks)
                qnext[nt2][ks] = *(const bf16x8*)(Qf + (((size_t)b * (N_ / 16) + (nG >> 4) + tn * 8 + w * 2 + nt2) * 2 + ks) * 512 + l * 8);

        // E = exp2(s) -> bf16, den accumulate, swizzled LDS write (R5 exact)
        #pragma unroll
        for (int nt2 = 0; nt2 < 2; ++nt2)
            #pragma unroll
            for (int f = 0; f < 4; ++f) {
                const float e0 = EXP2(s2[nt2][f][0]);
                const float e1 = EXP2(s2[nt2][f][1]);
                const float e2 = EXP2(s2[nt2][f][2]);
                const float e3 = EXP2(s2[nt2][f][3]);
                den[f] += (e0 + e1) + (e2 + e3);
                const uint u0 = __float_as_uint(e0) + 0x8000u;
                const uint u1 = __float_as_uint(e1) + 0x8000u;
                const uint u2 = __float_as_uint(e2) + 0x8000u;
                const uint u3 = __float_as_uint(e3) + 0x8000u;
                const int row = f * 16 + lr;
                const int g   = w * 4 + nt2 * 2 + (lg >> 1);
                *(uint2*)&Em[buf][row * NT + (((g + row) & 15) << 3) + ((lg & 1) << 2)] =
                    make_uint2((u1 & 0xFFFF0000u) | (u0 >> 16), (u3 & 0xFFFF0000u) | (u2 >> 16));
            }
        __syncthreads();

        // PV: out[o][m] += V[o][n] * E[n][m]
        __builtin_amdgcn_s_setprio(1);
        #pragma unroll
        for (int ks = 0; ks < 4; ++ks)
            #pragma unroll
            for (int f = 0; f < 4; ++f) {
                const int row = f * 16 + lr;
                const bf16x8 eb = *(const bf16x8*)&Em[buf][row * NT + (((ks * 4 + lg + row) & 15) << 3)];
                oacc[f] = MFMA(vh[ks], eb, oacc[f]);
            }
        __builtin_amdgcn_s_setprio(0);

        #pragma unroll
        for (int nt2 = 0; nt2 < 2; ++nt2) {
            qcur[nt2][0] = qnext[nt2][0];
            qcur[nt2][1] = qnext[nt2][1];
        }
    }

    // ---- epilogue (R4-verified partial write; no LDS reuse) ----
    #pragma unroll
    for (int f = 0; f < 4; ++f) {
        den[f] += __shfl_xor(den[f], 16);
        den[f] += __shfl_xor(den[f], 32);
    }
    __syncthreads();
    if (lg == 0)
        #pragma unroll
        for (int f = 0; f < 4; ++f) red[w][f * 16 + lr] = den[f];
    __syncthreads();

    const int pb = b * SPLITN + p;
    if (w == 0 && lg == 0)
        #pragma unroll
        for (int f = 0; f < 4; ++f)
            pden[(size_t)pb * N_ + m0 + f * 16 + lr] =
                red[0][f * 16 + lr] + red[1][f * 16 + lr] + red[2][f * 16 + lr] + red[3][f * 16 + lr];

    #pragma unroll
    for (int f = 0; f < 4; ++f)
        #pragma unroll
        for (int r = 0; r < 4; ++r) {
            const int o = w * 16 + lg * 4 + r;
            pacc[((size_t)pb * C_ + o) * N_ + m0 + f * 16 + lr] = oacc[f][r];
        }
}

// ---------------------------------------------------------------------------
// Combine: out = sum_p pacc / sum_p pden (float4 along m), SPLITN=2
// ---------------------------------------------------------------------------
__global__ __launch_bounds__(256) void combine_kernel(
    const float* __restrict__ pacc, const float* __restrict__ pden,
    float* __restrict__ out)
{
    const int idx = blockIdx.x * 256 + threadIdx.x;
    const int m4 = idx & (N_ / 4 - 1);
    const int o  = (idx >> 10) & 63;
    const int b  = idx >> 16;

    float4 s = make_float4(0.f, 0.f, 0.f, 0.f);
    float4 d = make_float4(0.f, 0.f, 0.f, 0.f);
    #pragma unroll
    for (int p = 0; p < SPLITN; ++p) {
        const float4 a = *(const float4*)(pacc + (((size_t)(b * SPLITN + p)) * C_ + o) * N_ + m4 * 4);
        const float4 e = *(const float4*)(pden + ((size_t)(b * SPLITN + p)) * N_ + m4 * 4);
        s.x += a.x; s.y += a.y; s.z += a.z; s.w += a.w;
        d.x += e.x; d.y += e.y; d.z += e.z; d.w += e.w;
    }
    *(float4*)(out + ((size_t)b * C_ + o) * N_ + m4 * 4) =
        make_float4(s.x / d.x, s.y / d.y, s.z / d.z, s.w / d.w);
}

// ---------------------------------------------------------------------------
extern "C" void kernel_launch(void* const* d_in, const int* in_sizes, int n_in,
                              void* d_out, int out_size, void* d_ws, size_t ws_size,
                              hipStream_t stream)
{
    const float* x  = (const float*)d_in[0];
    const float* Wq = (const float*)d_in[1];
    const float* Wk = (const float*)d_in[2];
    const float* Wv = (const float*)d_in[3];
    float* out = (float*)d_out;

    const size_t NE = (size_t)B_ * N_ * C_;   // 1M elements per bf16 array
    ushort* Qf = (ushort*)d_ws;
    ushort* Kf = Qf + NE;
    ushort* Vf = Kf + NE;
    float* pacc = (float*)(Vf + NE);                       // [B*2][64][N] = 8 MB
    float* pden = pacc + (size_t)B_ * SPLITN * C_ * N_;    // [B*2][N]

    qkv_mfma<<<B_ * (N_ / 32), 256, 0, stream>>>(x, Wq, Wk, Wv, Qf, Kf, Vf);
    attn_mfma<<<B_ * (N_ / MT) * SPLITN, 256, 0, stream>>>(Qf, Kf, Vf, pacc, pden);
    combine_kernel<<<B_ * C_ * N_ / 1024, 256, 0, stream>>>(pacc, pden, out);
}